// Round 4
// baseline (289.376 us; speedup 1.0000x reference)
//
#include <hip/hip_runtime.h>
#include <hip/hip_bf16.h>

// ---------------------------------------------------------------------------
// AdaptiveEmbedding: 3-cluster adaptive input embedding.
//   ids in [0,20000)      -> emb0[id] (1024), padding row 0 is zero
//   ids in [20000,60000)  -> proj1(1024x256) @ emb1[id-20000]
//   ids in [60000,128000) -> proj2(1024x64)  @ emb2[id-60000]
// Scaled by sqrt(1024)=32. Each out row written exactly once.
//
// R6 -> R7: fused was 83.8us @ 2.25TB/s, Occ ~20% (=6.4 waves/CU avg),
// MfmaUtil 3.3 / VALU 6.7 -> per-item latency chains with only 2 resident
// 8-wave blocks/CU (VGPR=128 cap) and ~10us/item. Fix: MORE CONCURRENT,
// SMALLER ITEMS: M=16-token tiles (acc halves to 32 VGPR), 256-thr/4-wave
// blocks owning a 512-dim half, __launch_bounds__(256,5) -> 5 blocks/CU
// resident (20 waves). Lists now int2 (tok,loc): removes one dependent
// global-load level from stage + copy. Copy items = 4 rows with 4
// independent chains per thread.
// ---------------------------------------------------------------------------

typedef __attribute__((ext_vector_type(4))) float        float4v;
typedef __attribute__((ext_vector_type(8))) short        short8;
typedef __attribute__((ext_vector_type(2))) unsigned int uint2v;
typedef __attribute__((ext_vector_type(2))) int          int2v;

#define D_MODEL 1024

__device__ __forceinline__ short f2bf(float x) {
    // round-to-nearest-even f32 -> bf16 (inputs are finite)
    unsigned u = __builtin_bit_cast(unsigned, x);
    unsigned r = u + 0x7fffu + ((u >> 16) & 1u);
    return (short)(r >> 16);
}

__device__ __forceinline__ uint2v pack4(float4v v) {
    uint2v r;
    r[0] = (unsigned)(unsigned short)f2bf(v[0]) | ((unsigned)(unsigned short)f2bf(v[1]) << 16);
    r[1] = (unsigned)(unsigned short)f2bf(v[2]) | ((unsigned)(unsigned short)f2bf(v[3]) << 16);
    return r;
}

// ------------------ partition (3 int2 lists) + proj->bf16 conversion --------
// 1024-thread blocks.
// blocks [0, pb)           : partition ids into l0/l1/l2 as int2 {tok, loc}.
//   two-level aggregation: ballot -> per-wave counts in LDS -> per-block scan
//   -> ONE atomicAdd per block per cluster -> fan bases out via LDS.
// blocks [pb, pb+64)       : proj1 (1024x256 fp32) -> bf16, 1 float4/thread
// blocks [pb+64, pb+80)    : proj2 (1024x64  fp32) -> bf16
__global__ __launch_bounds__(1024)
void prep_k(const int* __restrict__ ids, int n, int pb,
            int* __restrict__ cnt,
            int2v* __restrict__ l0, int2v* __restrict__ l1, int2v* __restrict__ l2,
            const float* __restrict__ proj1, const float* __restrict__ proj2,
            uint2v* __restrict__ p1bf, uint2v* __restrict__ p2bf)
{
    const int b = blockIdx.x;
    if (b >= pb) {
        int bb = b - pb;
        if (bb < 64) {
            int t = bb * 1024 + threadIdx.x;               // 65536 float4s
            p1bf[t] = pack4(((const float4v*)proj1)[t]);
        } else {
            int t = (bb - 64) * 1024 + threadIdx.x;        // 16384 float4s
            p2bf[t] = pack4(((const float4v*)proj2)[t]);
        }
        return;
    }

    __shared__ int s_wcnt[16][3];    // per-wave counts
    __shared__ int s_wbase[16][3];   // exclusive scan over waves
    __shared__ int s_base[3];        // block's global base per cluster

    const int tid  = threadIdx.x;
    const int wave = tid >> 6;       // 0..15
    const int lane = tid & 63;
    const int i    = b * 1024 + tid;

    int id = (i < n) ? ids[i] : -1;
    bool is0 = (i < n) && (id < 20000);
    bool is1 = (i < n) && (id >= 20000) && (id < 60000);
    bool is2 = (i < n) && (id >= 60000);
    unsigned long long ltmask = (lane == 0) ? 0ull : (~0ull >> (64 - lane));

    unsigned long long m0 = __ballot(is0);
    unsigned long long m1 = __ballot(is1);
    unsigned long long m2 = __ballot(is2);
    if (lane == 0) {
        s_wcnt[wave][0] = __popcll(m0);
        s_wcnt[wave][1] = __popcll(m1);
        s_wcnt[wave][2] = __popcll(m2);
    }
    __syncthreads();

    if (tid < 3) {
        const int c = tid;
        int run = 0;
#pragma unroll
        for (int w = 0; w < 16; w++) { s_wbase[w][c] = run; run += s_wcnt[w][c]; }
        // counter mapping: cluster1->cnt[0], cluster2->cnt[1], cluster0->cnt[2]
        const int gidx = (c == 0) ? 2 : (c - 1);
        s_base[c] = atomicAdd(&cnt[gidx], run);
    }
    __syncthreads();

    if (is0) l0[s_base[0] + s_wbase[wave][0] + __popcll(m0 & ltmask)] = (int2v){i, id};
    if (is1) l1[s_base[1] + s_wbase[wave][1] + __popcll(m1 & ltmask)] = (int2v){i, id - 20000};
    if (is2) l2[s_base[2] + s_wbase[wave][2] + __popcll(m2 & ltmask)] = (int2v){i, id - 60000};
}

// -------------------------- projected-cluster GEMM item ---------------------
// Item: 16 gathered tokens x 512 dims (half of d_model), 4 waves (256 thr).
// Wave w owns dims [dimh*512 + w*128, +128) as 8 MFMA n-tiles.
// A (16 rows x K) LDS-staged coalesced, fp32->bf16 on stage, row stride K+8.
// B is pre-converted bf16 in ws (L2-resident: 512KB / 128KB).
// MFMA 16x16x32 bf16 fragment layouts (verified m89 mappings):
//   A: lane holds A[m = lane&15][k = (lane>>4)*8 + j], j=0..7
//   B: lane holds B[k = (lane>>4)*8 + j][n = lane&15]  (= P[n][k], row-major P)
//   D: acc[reg r] = D[row = (lane>>4)*4 + r][col = lane&15]
template<int K>
__device__ __forceinline__
void gemm_item(int tile, int dimh,
               const float* __restrict__ table,   // [rows, K] fp32
               const short* __restrict__ pbf,     // [1024, K] bf16
               const int2v* __restrict__ list,    // {tok, loc}
               int count,
               float* __restrict__ out,
               int2v* s_tl, short* s_a)
{
    constexpr int PK = K + 8;          // padded LDS row stride (shorts)
    const int m_base = tile * 16;
    const int tid = threadIdx.x;
    if (tid < 16) {
        int m = m_base + tid;
        s_tl[tid] = (m < count) ? list[m] : (int2v){-1, 0};
    }
    __syncthreads();

    // ---- stage A: 16 rows x K fp32 -> bf16 LDS. 16 thr/row.
    {
        const int row = tid >> 4;                       // 0..15
        const int c   = tid & 15;
        const float* src = table + (size_t)s_tl[row][1] * K + c * (K / 16);
        short*       dst = s_a + row * PK + c * (K / 16);
        if constexpr (K == 256) {                       // 16 floats / thread
            const float4v* s4 = (const float4v*)src;
            float4v f0 = s4[0], f1 = s4[1], f2 = s4[2], f3 = s4[3];
            uint2v* d2 = (uint2v*)dst;
            d2[0] = pack4(f0); d2[1] = pack4(f1);
            d2[2] = pack4(f2); d2[3] = pack4(f3);
        } else {                                        // K == 64: 4 floats
            float4v f0 = *(const float4v*)src;
            *(uint2v*)dst = pack4(f0);
        }
    }
    __syncthreads();

    const int lane = tid & 63;
    const int wave = tid >> 6;     // 0..3
    const int col  = lane & 15;
    const int quad = lane >> 4;    // 0..3
    const int nb   = dimh * 512 + wave * 128;   // this wave's dim base

    const short* arow  = s_a + col * PK + quad * 8;
    const short* bbase = pbf + (size_t)(nb + col) * K + quad * 8;

    float4v acc[8];
#pragma unroll
    for (int i = 0; i < 8; i++) acc[i] = (float4v){0.f, 0.f, 0.f, 0.f};

#pragma unroll
    for (int ks = 0; ks < K; ks += 32) {
        short8 a = *(const short8*)(arow + ks);   // ds_read_b128
#pragma unroll
        for (int nt = 0; nt < 8; nt++) {
            short8 b = *(const short8*)(bbase + (size_t)nt * 16 * K + ks);
            acc[nt] = __builtin_amdgcn_mfma_f32_16x16x32_bf16(a, b, acc[nt], 0, 0, 0);
        }
    }

#pragma unroll
    for (int r = 0; r < 4; r++) {
        int row = quad * 4 + r;
        if (m_base + row < count) {
            float* orow = out + (size_t)s_tl[row][0] * D_MODEL + nb + col;
#pragma unroll
            for (int nt = 0; nt < 8; nt++) orow[nt * 16] = acc[nt][r] * 32.0f;
        }
    }
    __syncthreads();   // s_tl/s_a reused by next grid-stride iteration
}

// -------------------------- cluster-0 copy item (4 rows / 256 thr) ----------
__device__ __forceinline__
void copy_item(int item, const int2v* __restrict__ l0, int count0,
               const float* __restrict__ emb0, float* __restrict__ out)
{
    int r = item * 4 + (threadIdx.x >> 6);       // 4 rows per item
    if (r < count0) {
        int2v tl = l0[r];                        // {tok, id} - one 8B load
        const float4v* src = (const float4v*)(emb0 + (size_t)tl[1] * D_MODEL);
        float4v*       dst = (float4v*)(out + (size_t)tl[0] * D_MODEL);
        int c = threadIdx.x & 63;
        // 4 independent load chains per thread (row is 256 float4s)
        float4v v0 = src[c], v1 = src[c + 64], v2 = src[c + 128], v3 = src[c + 192];
        dst[c]       = v0 * 32.0f;
        dst[c + 64]  = v1 * 32.0f;
        dst[c + 128] = v2 * 32.0f;
        dst[c + 192] = v3 * 32.0f;
    }
}

// -------------------------- fused consumer ----------------------------------
// One grid-stride kernel over a runtime work-list:
//   items [0, g1)          : cluster-1 GEMM items (K=256), 2 dim-halves/tile
//   items [g1, g1+g2)      : cluster-2 GEMM items (K=64)
//   items [g1+g2, total)   : cluster-0 4-row copies
// All items write disjoint out regions; lists/cnt/projbf produced by prep_k.
// 256-thr blocks, min 5 waves/EU -> 5 resident blocks/CU (vs 2 at R6).
__global__ __launch_bounds__(256, 5)
void fused_main(const float* __restrict__ emb0,
                const float* __restrict__ emb1,
                const float* __restrict__ emb2,
                const short* __restrict__ p1bf,
                const short* __restrict__ p2bf,
                const int2v* __restrict__ l0,
                const int2v* __restrict__ l1,
                const int2v* __restrict__ l2,
                const int* __restrict__ cnt,
                float* __restrict__ out)
{
    __shared__ int2v s_tl[16];
    __shared__ short s_a[16 * 264];   // 8.4 KB: A tile, bf16, padded rows

    const int c1 = cnt[0];
    const int c2 = cnt[1];
    const int c0 = cnt[2];
    const int g1 = ((c1 + 15) >> 4) * 2;   // two dim-halves per 16-token tile
    const int g2 = ((c2 + 15) >> 4) * 2;
    const int tc = (c0 + 3) >> 2;
    const int total = g1 + g2 + tc;

    for (int w = blockIdx.x; w < total; w += gridDim.x) {
        if (w < g1) {
            gemm_item<256>(w >> 1, w & 1, emb1, p1bf, l1, c1, out, s_tl, s_a);
        } else if (w < g1 + g2) {
            int u = w - g1;
            gemm_item<64>(u >> 1, u & 1, emb2, p2bf, l2, c2, out, s_tl, s_a);
        } else {
            copy_item(w - g1 - g2, l0, c0, emb0, out);
        }
    }
}

// ---------------------------------------------------------------------------
extern "C" void kernel_launch(void* const* d_in, const int* in_sizes, int n_in,
                              void* d_out, int out_size, void* d_ws, size_t ws_size,
                              hipStream_t stream)
{
    const int*   ids   = (const int*)  d_in[0];
    const float* emb0  = (const float*)d_in[1];
    const float* emb1  = (const float*)d_in[2];
    const float* emb2  = (const float*)d_in[3];
    const float* proj1 = (const float*)d_in[4];
    const float* proj2 = (const float*)d_in[5];
    float*       out   = (float*)d_out;
    const int n = in_sizes[0];                 // 32768 tokens

    // ws layout: [0,256) counters | l0,l1,l2 (n int2 each) | proj1bf | proj2bf
    int*   cnt  = (int*)d_ws;
    int2v* l0   = (int2v*)((char*)d_ws + 256);
    int2v* l1   = l0 + n;
    int2v* l2   = l1 + n;
    size_t poff = (256 + (size_t)3 * n * 8 + 255) & ~(size_t)255;
    short* p1bf = (short*)((char*)d_ws + poff);
    short* p2bf = p1bf + 1024 * 256;

    const int pb = (n + 1023) / 1024;          // partition blocks (1024 thr)

    hipMemsetAsync(cnt, 0, 4 * sizeof(int), stream);
    prep_k<<<pb + 64 + 16, 1024, 0, stream>>>(ids, n, pb, cnt, l0, l1, l2,
                                              proj1, proj2,
                                              (uint2v*)p1bf, (uint2v*)p2bf);
    fused_main<<<4096, 256, 0, stream>>>(emb0, emb1, emb2,
                                         p1bf, p2bf, l0, l1, l2, cnt, out);
}